// Round 9
// baseline (217.013 us; speedup 1.0000x reference)
//
#include <hip/hip_runtime.h>
#include <hip/hip_fp16.h>
#include <math.h>

// ---------------- problem constants ----------------
// x: (16, 2048, 64) f32  -> out: (16, 2048, 64, 5) f32
// scales = {1,27,76,167,336}; morlet int_psi, n=1024, [-8,8]
#define NB    16
#define T     2048
#define NC    64
#define NROWS (NB*NC)     // 1024
#define PADL2 2696        // left zero-pad (halves), mult of 8
#define XSH_N 7600        // 2696+2048+pad; max prefetch idx 7535 < 7600

// Unified global-k chunk axis: chunk c covers k in [32c,32c+32), c in [0,169).
// k = b + i + posoff, posoff = 2695-8s. Exec order: largest scale first
// (nested ranges -> alive set is always a prefix of exec order).
//   sl:      0      1      2      3      4
//   scale:   336    167    76     27     1
//   CLO:     0      42     65     77     83
//   KS2:     5408   2720   1248   480    64     (=32*NCH, W row stride)
//   WOFF:    0      86528  130048 150016 157696 (halves; 158720 used)
//   outslot: 4      3      2      1      0
// W padded to 158976 halves: sl=4's depth-2 prefetch overruns to idx 158815.
#define WTOT_U4 19872

// ws layout (bytes):
//   0        : __half W[158976]                    (~310 KB)
//   512 KB   : __half xT[1024][2048]               (4 MB)
//   512KB+4MB: __half outT2[16][128][64][5][16]    (20 MB)  [n][tb][c][s][tt]
#define WS_XT    (1u<<19)
#define WS_OUTT  ((1u<<19) + (1u<<22))

typedef _Float16 half8  __attribute__((ext_vector_type(8)));
typedef _Float16 half4v __attribute__((ext_vector_type(4)));
typedef float    f32x4  __attribute__((ext_vector_type(4)));

// ---------------- kernel 1: fused W-build (block 0) + transpose (blocks 1..128) ----------------
// init: replicates reference float64 arithmetic EXACTLY (rounds 1/2/4 verified):
//   t = linspace(-8,8,1024); step = t[1]-t[0]  ((-8+16/1023)+8 roundtrip!)
//   j_i = int64(i/(s*step)); taps g_i over i in [0,L], L=16s+1:
//   g_0=+sq*k[0]; g_i=sq*(k[j_i]-k[j_{i-1}]); g_L=-sq*k[j_{L-1}];  sq=sqrt(s)
//   Scatter: W[sl][b][ b + i + posoff - 32*CLO[sl] ] = g_i  for b in [0,16).
__global__ __launch_bounds__(1024) void cwt_prep(const float* __restrict__ x,
                                                 __half* __restrict__ xT,
                                                 __half* __restrict__ W) {
    __shared__ double ps[1024];
    __shared__ double sc[1024];
    __shared__ float  k32[1024];
    __shared__ float  tile4[4][64 * 65];
    const int tid = threadIdx.x;

    if (blockIdx.x == 0) {
        uint4* W4 = (uint4*)W;
        const uint4 z = make_uint4(0u, 0u, 0u, 0u);
        for (int i = tid; i < WTOT_U4; i += 1024) W4[i] = z;

        const double delta = 16.0 / 1023.0;
        double t = (tid == 1023) ? 8.0 : (-8.0 + delta * (double)tid);
        ps[tid] = exp(-0.5 * t * t) * cos(5.0 * t);
        __syncthreads();

        double* a = ps; double* b = sc;
        for (int off = 1; off < 1024; off <<= 1) {
            double v = a[tid];
            if (tid >= off) v += a[tid - off];
            b[tid] = v;
            __syncthreads();
            double* tmp = a; a = b; b = tmp;
        }
        const double step = ((-8.0 + delta) + 8.0);   // NOT exactly 16/1023
        k32[tid] = (float)(a[tid] * step);
        __syncthreads();

        constexpr int SCe[5]   = {336, 167, 76, 27, 1};
        constexpr int KS2[5]   = {5408, 2720, 1248, 480, 64};
        constexpr int WOFFe[5] = {0, 86528, 130048, 150016, 157696};
        constexpr int CLOe[5]  = {0, 42, 65, 77, 83};
        for (int sl = 0; sl < 5; ++sl) {
            const int s = SCe[sl];
            const int L = 16 * s + 1;
            const double c = (double)s * step;
            const float sq = (float)sqrt((double)s);
            const int posoff = PADL2 - 8 * s - 1;
            const int kb0 = posoff - 32 * CLOe[sl];
            __half* wb = W + WOFFe[sl];
            const int Ks = KS2[sl];
            for (int i = tid; i <= L; i += 1024) {
                float g; bool wr = true;
                if (i == 0) {
                    g = sq * k32[0];
                } else if (i == L) {
                    long long jl = (long long)((double)(L - 1) / c);
                    if (jl > 1023) jl = 1023;
                    g = -sq * k32[jl];
                } else {
                    long long j1 = (long long)((double)i / c);
                    long long j0 = (long long)((double)(i - 1) / c);
                    if (j1 > 1023) j1 = 1023;
                    if (j0 > 1023) j0 = 1023;
                    wr = (j1 > j0);
                    g = sq * (k32[j1] - k32[j0]);
                }
                if (wr) {
                    const __half hg = __float2half(g);
                    const int kb = kb0 + i;
                    #pragma unroll
                    for (int bb = 0; bb < 16; ++bb)
                        wb[bb * Ks + kb + bb] = hg;
                }
            }
        }
    } else {
        const int g    = tid >> 8;                // 0..3: tile within block
        const int t256 = tid & 255;
        const int ti   = (blockIdx.x - 1) * 4 + g;  // 0..511
        const int n    = ti >> 5;
        const int t0   = (ti & 31) << 6;
        float* tl = tile4[g];

        const float4* src = (const float4*)(x + ((size_t)(n * T + t0)) * NC);
        #pragma unroll
        for (int k = 0; k < 4; ++k) {
            float4 v = src[t256 + 256 * k];
            const int flat = (t256 + 256 * k) * 4;
            const int tt = flat >> 6, c = flat & 63;
            tl[tt * 65 + c + 0] = v.x;
            tl[tt * 65 + c + 1] = v.y;
            tl[tt * 65 + c + 2] = v.z;
            tl[tt * 65 + c + 3] = v.w;
        }
        __syncthreads();
        const int lane = t256 & 63, w4 = t256 >> 6;
        for (int cc = w4; cc < 64; cc += 4) {
            xT[((size_t)(n * 64 + cc)) * T + t0 + lane] = __float2half(tl[lane * 65 + cc]);
        }
    }
}

// ---------------- kernel 2: Toeplitz-block MFMA conv, in-block split-K ----------------
// Out_sl[16A+b] = sum_k W_sl[b][k-32*CLO] * xsh[16A+k].
// Block = 1 row (n,c), 4 waves = 2 t-halves (w) x 2 K-halves (kh):
//   kh=0 chunks [0,85), kh=1 chunks [85,169)  (158 vs 152 chunk-scales).
// Same A/B/MFMA totals as round 6 but 16 waves/CU = 4 waves/SIMD (2x latency
// hiding). After conv: kh=1 dumps acc to LDS (reused xsh, stride-20 padded),
// kh=0 adds and runs the verified round-6 epilogue to outT2 (f16, MFMA-native
// layout; fix kernel does the final coalesced transpose).
// VGPR budget: round-6 body measured 120 -> fits the 128 cap of (256,4).
template<int N, int DEPTH>
__device__ __forceinline__ void conv_seg(int c0, int c1,
                                         const _Float16* __restrict__ xb,
                                         const _Float16* const (&ap)[5],
                                         f32x4 (&acc)[5][4]) {
    half8 A[DEPTH][N];
    half8 B[DEPTH][4];
    #pragma unroll
    for (int d = 0; d < DEPTH; ++d) {
        const int ko = (c0 + d) << 5;
        #pragma unroll
        for (int sl = 0; sl < N; ++sl) A[d][sl] = *(const half8*)(ap[sl] + ko);
        #pragma unroll
        for (int j = 0; j < 4; ++j)   B[d][j]  = *(const half8*)(xb + 256 * j + ko);
    }
    int c = c0;
    for (; c + DEPTH <= c1; c += DEPTH) {
        #pragma unroll
        for (int d = 0; d < DEPTH; ++d) {
            #pragma unroll
            for (int sl = 0; sl < N; ++sl) {
                acc[sl][0] = __builtin_amdgcn_mfma_f32_16x16x32_f16(A[d][sl], B[d][0], acc[sl][0], 0, 0, 0);
                acc[sl][1] = __builtin_amdgcn_mfma_f32_16x16x32_f16(A[d][sl], B[d][1], acc[sl][1], 0, 0, 0);
                acc[sl][2] = __builtin_amdgcn_mfma_f32_16x16x32_f16(A[d][sl], B[d][2], acc[sl][2], 0, 0, 0);
                acc[sl][3] = __builtin_amdgcn_mfma_f32_16x16x32_f16(A[d][sl], B[d][3], acc[sl][3], 0, 0, 0);
            }
            const int ko = (c + DEPTH + d) << 5;   // prefetch (unclamped, memory-safe)
            #pragma unroll
            for (int sl = 0; sl < N; ++sl) A[d][sl] = *(const half8*)(ap[sl] + ko);
            #pragma unroll
            for (int j = 0; j < 4; ++j)   B[d][j]  = *(const half8*)(xb + 256 * j + ko);
        }
    }
    // tail: r = c1-c in [0, DEPTH); slots d<r hold valid chunks c+d
    #pragma unroll
    for (int d = 0; d < DEPTH; ++d) {
        if (d < c1 - c) {
            #pragma unroll
            for (int sl = 0; sl < N; ++sl) {
                acc[sl][0] = __builtin_amdgcn_mfma_f32_16x16x32_f16(A[d][sl], B[d][0], acc[sl][0], 0, 0, 0);
                acc[sl][1] = __builtin_amdgcn_mfma_f32_16x16x32_f16(A[d][sl], B[d][1], acc[sl][1], 0, 0, 0);
                acc[sl][2] = __builtin_amdgcn_mfma_f32_16x16x32_f16(A[d][sl], B[d][2], acc[sl][2], 0, 0, 0);
                acc[sl][3] = __builtin_amdgcn_mfma_f32_16x16x32_f16(A[d][sl], B[d][3], acc[sl][3], 0, 0, 0);
            }
        }
    }
}

__global__ __launch_bounds__(256, 4) void cwt_conv_mfma(const __half* __restrict__ xT,
                                                        const __half* __restrict__ Wg,
                                                        __half* __restrict__ outT) {
    constexpr int KS2[5]   = {5408, 2720, 1248, 480, 64};
    constexpr int WOFFe[5] = {0, 86528, 130048, 150016, 157696};
    constexpr int CLOe[5]  = {0, 42, 65, 77, 83};
    constexpr int OS[5]    = {4, 3, 2, 1, 0};

    __shared__ _Float16 xsh[XSH_N];               // 15200 B; reused as f32 reduce buf
    __shared__ _Float16 ostage[2048];             // 4096 B (1024 per t-half wave)
    const int tid  = threadIdx.x;
    const int row  = blockIdx.x;
    const int nidx = row >> 6;                    // batch n
    const int cidx = row & 63;                    // channel c
    const int lane = tid & 63;
    const int v    = tid >> 6;                    // wave 0..3
    const int w    = v & 1;                       // t-half: A-cols [64w, 64w+64)
    const int kh   = v >> 1;                      // K-half
    const int mcol = lane & 15;                   // A-frag: W row b;  B-frag: col n
    const int grp  = lane >> 4;                   // k-subgroup

    // ---- stage padded signal row (fp16); data uint4 range [337, 593) ----
    {
        uint4* x4 = (uint4*)xsh;
        const uint4 z = make_uint4(0u, 0u, 0u, 0u);
        for (int i = tid; i < XSH_N / 8; i += 256)
            if (i < PADL2 / 8 || i >= (PADL2 + T) / 8) x4[i] = z;
        x4[PADL2 / 8 + tid] = ((const uint4*)(xT + (size_t)row * T))[tid];
    }
    __syncthreads();

    // per-lane operand bases
    const _Float16* xb = xsh + 1024 * w + 16 * mcol + 8 * grp;  // tiles at +0,+256,+512,+768
    const _Float16* ap[5];
    #pragma unroll
    for (int sl = 0; sl < 5; ++sl)
        ap[sl] = (const _Float16*)Wg + WOFFe[sl] + mcol * KS2[sl] + 8 * grp
                 - (CLOe[sl] << 5);

    f32x4 acc[5][4];
    #pragma unroll
    for (int sl = 0; sl < 5; ++sl)
        #pragma unroll
        for (int j = 0; j < 4; ++j)
            acc[sl][j] = (f32x4){0.f, 0.f, 0.f, 0.f};

    // constant-alive-count segments; alive:
    // 336:[0,169) 167:[42,127) 76:[65,104) 27:[77,92) 1:[83,85)
    if (kh == 0) {
        conv_seg<1,3>(  0,  42, xb, ap, acc);
        conv_seg<2,3>( 42,  65, xb, ap, acc);
        conv_seg<3,2>( 65,  77, xb, ap, acc);
        conv_seg<4,2>( 77,  83, xb, ap, acc);
        conv_seg<5,2>( 83,  85, xb, ap, acc);
    } else {
        conv_seg<4,2>( 85,  92, xb, ap, acc);
        conv_seg<3,2>( 92, 104, xb, ap, acc);
        conv_seg<2,3>(104, 127, xb, ap, acc);
        conv_seg<1,3>(127, 169, xb, ap, acc);
    }

    // ---- split-K reduction: kh=1 -> LDS (reused xsh), kh=0 adds ----
    __syncthreads();                               // all B-reads done; xsh reusable
    float* red = reinterpret_cast<float*>(xsh);    // [(w*64+lane)*20 + 4j+r], 10.2 KB
    float* rb  = red + (w * 64 + lane) * 20;       // stride 20: 16B-aligned, banks spread
    #pragma unroll
    for (int sl = 0; sl < 5; ++sl) {
        if (kh == 1) {
            #pragma unroll
            for (int j = 0; j < 4; ++j) *(f32x4*)(rb + 4 * j) = acc[sl][j];
        }
        __syncthreads();
        if (kh == 0) {
            #pragma unroll
            for (int j = 0; j < 4; ++j) acc[sl][j] += *(const f32x4*)(rb + 4 * j);
        }
        __syncthreads();
    }

    // ---- epilogue (round-6 verified), kh=0 waves only ----
    // D col=lane&15 -> A-col n, row=grp*4+r -> b; t' = 1024w + 256j + 16n + b.
    // outT2 [n][tb][c][s][16]: lane l owns tb-local = l.
    if (kh == 0) {
        _Float16* os = ostage + 1024 * w;          // wave-local, no barrier needed
        #pragma unroll
        for (int sl = 0; sl < 5; ++sl) {
            #pragma unroll
            for (int j = 0; j < 4; ++j) {
                half4v h;
                #pragma unroll
                for (int r = 0; r < 4; ++r) h[r] = (_Float16)acc[sl][j][r];
                *(half4v*)(os + 256 * j + 16 * mcol + 4 * grp) = h;
            }
            half8 o0 = *(const half8*)(os + 16 * lane);
            half8 o1 = *(const half8*)(os + 16 * lane + 8);
            __half* ob = outT + ((size_t)(((nidx * 128 + 64 * w + lane) * 64 + cidx) * 5 + OS[sl])) * 16;
            *(half8*)(ob)     = o0;
            *(half8*)(ob + 8) = o1;
        }
    }
}

// ---------------- kernel 3: outT2[n][tb][c][s][16] -> out[n][t][c][s] ----------------
// Read side fully contiguous (10 KB per block); LDS transposes [c][s][tt]->[tt][c][s].
__global__ __launch_bounds__(256) void cwt_fix(const __half* __restrict__ outT,
                                               float* __restrict__ out) {
    __shared__ float tile[16 * 320];              // [tt][c*5+s]
    const int b  = blockIdx.x;                    // 0..2047
    const int n  = b >> 7;
    const int tb = b & 127;
    const int tid = threadIdx.x;

    const uint4* src = (const uint4*)(outT + (size_t)(n * 128 + tb) * 5120);
    for (int i = tid; i < 640; i += 256) {
        uint4 v = src[i];                         // 8 halves: (c,s) fixed, tt0..tt0+7
        const __half* h = (const __half*)&v;
        const int h0  = i * 8;
        const int sg  = h0 >> 4;                  // c*5+s
        const int tt0 = h0 & 15;                  // 0 or 8
        #pragma unroll
        for (int k = 0; k < 8; ++k) tile[(tt0 + k) * 320 + sg] = __half2float(h[k]);
    }
    __syncthreads();
    float4* dst = (float4*)(out + (size_t)(n * 2048 + tb * 16) * 320);
    const float4* tl = (const float4*)tile;
    for (int k = tid; k < 1280; k += 256) dst[k] = tl[k];
}

// ---------------- launch ----------------
extern "C" void kernel_launch(void* const* d_in, const int* in_sizes, int n_in,
                              void* d_out, int out_size, void* d_ws, size_t ws_size,
                              hipStream_t stream) {
    const float* x = (const float*)d_in[0];
    float* out = (float*)d_out;
    char* ws = (char*)d_ws;

    __half* W    = (__half*)ws;
    __half* xT   = (__half*)(ws + WS_XT);
    __half* outT = (__half*)(ws + WS_OUTT);

    cwt_prep<<<129, 1024, 0, stream>>>(x, xT, W);
    cwt_conv_mfma<<<NROWS, 256, 0, stream>>>(xT, W, outT);
    cwt_fix<<<2048, 256, 0, stream>>>(outT, out);
}

// Round 10
// 171.276 us; speedup vs baseline: 1.2670x; 1.2670x over previous
//
#include <hip/hip_runtime.h>
#include <hip/hip_fp16.h>
#include <math.h>

// ---------------- problem constants ----------------
// x: (16, 2048, 64) f32  -> out: (16, 2048, 64, 5) f32
// scales = {1,27,76,167,336}; morlet int_psi, n=1024, [-8,8]
#define NB    16
#define T     2048
#define NC    64
#define NROWS (NB*NC)     // 1024
#define PADL2 2696        // left zero-pad (halves), mult of 8
#define XSH_N 7600        // 2696+2048+pad; max prefetch idx 7535 < 7600

// Unified global-k chunk axis: chunk c covers k in [32c,32c+32), c in [0,169).
// k = b + i + posoff, posoff = 2695-8s. Exec order: largest scale first
// (nested ranges -> alive set is always a prefix of exec order).
//   sl:      0      1      2      3      4
//   scale:   336    167    76     27     1
//   CLO:     0      42     65     77     83
//   KS2:     5408   2720   1248   480    64     (=32*NCH, W row stride)
//   WOFF:    0      86528  130048 150016 157696 (halves; 158720 used)
//   outslot: 4      3      2      1      0
// W padded to 158976 halves: sl=4's depth-2 prefetch overruns to idx 158815.
#define WTOT_U4 19872

// ws layout (bytes):
//   0        : __half W[158976]                    (~310 KB)
//   512 KB   : __half xT[1024][2048]               (4 MB)
//   512KB+4MB: __half outT2[16][128][64][5][16]    (20 MB)  [n][tb][c][s][tt]
#define WS_XT    (1u<<19)
#define WS_OUTT  ((1u<<19) + (1u<<22))

typedef _Float16 half8  __attribute__((ext_vector_type(8)));
typedef _Float16 half4v __attribute__((ext_vector_type(4)));
typedef float    f32x4  __attribute__((ext_vector_type(4)));

// ---------------- kernel 1: fused W-build (block 0) + transpose (blocks 1..128) ----------------
// init: replicates reference float64 arithmetic EXACTLY (rounds 1/2/4 verified):
//   t = linspace(-8,8,1024); step = t[1]-t[0]  ((-8+16/1023)+8 roundtrip!)
//   j_i = int64(i/(s*step)); taps g_i over i in [0,L], L=16s+1:
//   g_0=+sq*k[0]; g_i=sq*(k[j_i]-k[j_{i-1}]); g_L=-sq*k[j_{L-1}];  sq=sqrt(s)
//   Scatter: W[sl][b][ b + i + posoff - 32*CLO[sl] ] = g_i  for b in [0,16).
__global__ __launch_bounds__(1024) void cwt_prep(const float* __restrict__ x,
                                                 __half* __restrict__ xT,
                                                 __half* __restrict__ W) {
    __shared__ double ps[1024];
    __shared__ double sc[1024];
    __shared__ float  k32[1024];
    __shared__ float  tile4[4][64 * 65];
    const int tid = threadIdx.x;

    if (blockIdx.x == 0) {
        uint4* W4 = (uint4*)W;
        const uint4 z = make_uint4(0u, 0u, 0u, 0u);
        for (int i = tid; i < WTOT_U4; i += 1024) W4[i] = z;

        const double delta = 16.0 / 1023.0;
        double t = (tid == 1023) ? 8.0 : (-8.0 + delta * (double)tid);
        ps[tid] = exp(-0.5 * t * t) * cos(5.0 * t);
        __syncthreads();

        double* a = ps; double* b = sc;
        for (int off = 1; off < 1024; off <<= 1) {
            double v = a[tid];
            if (tid >= off) v += a[tid - off];
            b[tid] = v;
            __syncthreads();
            double* tmp = a; a = b; b = tmp;
        }
        const double step = ((-8.0 + delta) + 8.0);   // NOT exactly 16/1023
        k32[tid] = (float)(a[tid] * step);
        __syncthreads();

        constexpr int SCe[5]   = {336, 167, 76, 27, 1};
        constexpr int KS2[5]   = {5408, 2720, 1248, 480, 64};
        constexpr int WOFFe[5] = {0, 86528, 130048, 150016, 157696};
        constexpr int CLOe[5]  = {0, 42, 65, 77, 83};
        for (int sl = 0; sl < 5; ++sl) {
            const int s = SCe[sl];
            const int L = 16 * s + 1;
            const double c = (double)s * step;
            const float sq = (float)sqrt((double)s);
            const int posoff = PADL2 - 8 * s - 1;
            const int kb0 = posoff - 32 * CLOe[sl];
            __half* wb = W + WOFFe[sl];
            const int Ks = KS2[sl];
            for (int i = tid; i <= L; i += 1024) {
                float g; bool wr = true;
                if (i == 0) {
                    g = sq * k32[0];
                } else if (i == L) {
                    long long jl = (long long)((double)(L - 1) / c);
                    if (jl > 1023) jl = 1023;
                    g = -sq * k32[jl];
                } else {
                    long long j1 = (long long)((double)i / c);
                    long long j0 = (long long)((double)(i - 1) / c);
                    if (j1 > 1023) j1 = 1023;
                    if (j0 > 1023) j0 = 1023;
                    wr = (j1 > j0);
                    g = sq * (k32[j1] - k32[j0]);
                }
                if (wr) {
                    const __half hg = __float2half(g);
                    const int kb = kb0 + i;
                    #pragma unroll
                    for (int bb = 0; bb < 16; ++bb)
                        wb[bb * Ks + kb + bb] = hg;
                }
            }
        }
    } else {
        const int g    = tid >> 8;                // 0..3: tile within block
        const int t256 = tid & 255;
        const int ti   = (blockIdx.x - 1) * 4 + g;  // 0..511
        const int n    = ti >> 5;
        const int t0   = (ti & 31) << 6;
        float* tl = tile4[g];

        const float4* src = (const float4*)(x + ((size_t)(n * T + t0)) * NC);
        #pragma unroll
        for (int k = 0; k < 4; ++k) {
            float4 v = src[t256 + 256 * k];
            const int flat = (t256 + 256 * k) * 4;
            const int tt = flat >> 6, c = flat & 63;
            tl[tt * 65 + c + 0] = v.x;
            tl[tt * 65 + c + 1] = v.y;
            tl[tt * 65 + c + 2] = v.z;
            tl[tt * 65 + c + 3] = v.w;
        }
        __syncthreads();
        const int lane = t256 & 63, w4 = t256 >> 6;
        for (int cc = w4; cc < 64; cc += 4) {
            xT[((size_t)(n * 64 + cc)) * T + t0 + lane] = __float2half(tl[lane * 65 + cc]);
        }
    }
}

// ---------------- kernel 2: Toeplitz-block MFMA conv, in-block split-K ----------------
// Out_sl[16A+b] = sum_k W_sl[b][k-32*CLO] * xsh[16A+k].
// Block = 1 row (n,c), 4 waves = 2 t-halves (w) x 2 K-halves (kh):
//   kh=0 chunks [0,85), kh=1 chunks [85,169)  (158 vs 152 chunk-scales).
// Same A/B/MFMA totals as round 6 but 2x wave count -> better latency hiding.
// CRITICAL (rounds 8/9 lesson): NO min-waves in __launch_bounds__ — the body
// needs ~130-180 VGPR; any cap <=128 makes the allocator spill acc inside the
// MFMA loop (R9: VGPR=64, +390 MB scratch traffic, 2.3x slower). With cap 256
// the runtime occupancy self-selects 3-4 waves/SIMD from the actual count.
template<int N, int DEPTH>
__device__ __forceinline__ void conv_seg(int c0, int c1,
                                         const _Float16* __restrict__ xb,
                                         const _Float16* const (&ap)[5],
                                         f32x4 (&acc)[5][4]) {
    half8 A[DEPTH][N];
    half8 B[DEPTH][4];
    #pragma unroll
    for (int d = 0; d < DEPTH; ++d) {
        const int ko = (c0 + d) << 5;
        #pragma unroll
        for (int sl = 0; sl < N; ++sl) A[d][sl] = *(const half8*)(ap[sl] + ko);
        #pragma unroll
        for (int j = 0; j < 4; ++j)   B[d][j]  = *(const half8*)(xb + 256 * j + ko);
    }
    int c = c0;
    for (; c + DEPTH <= c1; c += DEPTH) {
        #pragma unroll
        for (int d = 0; d < DEPTH; ++d) {
            #pragma unroll
            for (int sl = 0; sl < N; ++sl) {
                acc[sl][0] = __builtin_amdgcn_mfma_f32_16x16x32_f16(A[d][sl], B[d][0], acc[sl][0], 0, 0, 0);
                acc[sl][1] = __builtin_amdgcn_mfma_f32_16x16x32_f16(A[d][sl], B[d][1], acc[sl][1], 0, 0, 0);
                acc[sl][2] = __builtin_amdgcn_mfma_f32_16x16x32_f16(A[d][sl], B[d][2], acc[sl][2], 0, 0, 0);
                acc[sl][3] = __builtin_amdgcn_mfma_f32_16x16x32_f16(A[d][sl], B[d][3], acc[sl][3], 0, 0, 0);
            }
            const int ko = (c + DEPTH + d) << 5;   // prefetch (unclamped, memory-safe)
            #pragma unroll
            for (int sl = 0; sl < N; ++sl) A[d][sl] = *(const half8*)(ap[sl] + ko);
            #pragma unroll
            for (int j = 0; j < 4; ++j)   B[d][j]  = *(const half8*)(xb + 256 * j + ko);
        }
    }
    // tail: r = c1-c in [0, DEPTH); slots d<r hold valid chunks c+d
    #pragma unroll
    for (int d = 0; d < DEPTH; ++d) {
        if (d < c1 - c) {
            #pragma unroll
            for (int sl = 0; sl < N; ++sl) {
                acc[sl][0] = __builtin_amdgcn_mfma_f32_16x16x32_f16(A[d][sl], B[d][0], acc[sl][0], 0, 0, 0);
                acc[sl][1] = __builtin_amdgcn_mfma_f32_16x16x32_f16(A[d][sl], B[d][1], acc[sl][1], 0, 0, 0);
                acc[sl][2] = __builtin_amdgcn_mfma_f32_16x16x32_f16(A[d][sl], B[d][2], acc[sl][2], 0, 0, 0);
                acc[sl][3] = __builtin_amdgcn_mfma_f32_16x16x32_f16(A[d][sl], B[d][3], acc[sl][3], 0, 0, 0);
            }
        }
    }
}

__global__ __launch_bounds__(256) void cwt_conv_mfma(const __half* __restrict__ xT,
                                                     const __half* __restrict__ Wg,
                                                     __half* __restrict__ outT) {
    constexpr int KS2[5]   = {5408, 2720, 1248, 480, 64};
    constexpr int WOFFe[5] = {0, 86528, 130048, 150016, 157696};
    constexpr int CLOe[5]  = {0, 42, 65, 77, 83};
    constexpr int OS[5]    = {4, 3, 2, 1, 0};

    __shared__ _Float16 xsh[XSH_N];               // 15200 B; reused as f32 reduce buf
    __shared__ _Float16 ostage[2048];             // 4096 B (1024 per t-half wave)
    const int tid  = threadIdx.x;
    const int row  = blockIdx.x;
    const int nidx = row >> 6;                    // batch n
    const int cidx = row & 63;                    // channel c
    const int lane = tid & 63;
    const int v    = tid >> 6;                    // wave 0..3
    const int w    = v & 1;                       // t-half: A-cols [64w, 64w+64)
    const int kh   = v >> 1;                      // K-half
    const int mcol = lane & 15;                   // A-frag: W row b;  B-frag: col n
    const int grp  = lane >> 4;                   // k-subgroup

    // ---- stage padded signal row (fp16); data uint4 range [337, 593) ----
    {
        uint4* x4 = (uint4*)xsh;
        const uint4 z = make_uint4(0u, 0u, 0u, 0u);
        for (int i = tid; i < XSH_N / 8; i += 256)
            if (i < PADL2 / 8 || i >= (PADL2 + T) / 8) x4[i] = z;
        x4[PADL2 / 8 + tid] = ((const uint4*)(xT + (size_t)row * T))[tid];
    }
    __syncthreads();

    // per-lane operand bases
    const _Float16* xb = xsh + 1024 * w + 16 * mcol + 8 * grp;  // tiles at +0,+256,+512,+768
    const _Float16* ap[5];
    #pragma unroll
    for (int sl = 0; sl < 5; ++sl)
        ap[sl] = (const _Float16*)Wg + WOFFe[sl] + mcol * KS2[sl] + 8 * grp
                 - (CLOe[sl] << 5);

    f32x4 acc[5][4];
    #pragma unroll
    for (int sl = 0; sl < 5; ++sl)
        #pragma unroll
        for (int j = 0; j < 4; ++j)
            acc[sl][j] = (f32x4){0.f, 0.f, 0.f, 0.f};

    // constant-alive-count segments; alive:
    // 336:[0,169) 167:[42,127) 76:[65,104) 27:[77,92) 1:[83,85)
    if (kh == 0) {
        conv_seg<1,3>(  0,  42, xb, ap, acc);
        conv_seg<2,3>( 42,  65, xb, ap, acc);
        conv_seg<3,2>( 65,  77, xb, ap, acc);
        conv_seg<4,2>( 77,  83, xb, ap, acc);
        conv_seg<5,2>( 83,  85, xb, ap, acc);
    } else {
        conv_seg<4,2>( 85,  92, xb, ap, acc);
        conv_seg<3,2>( 92, 104, xb, ap, acc);
        conv_seg<2,3>(104, 127, xb, ap, acc);
        conv_seg<1,3>(127, 169, xb, ap, acc);
    }

    // ---- split-K reduction: kh=1 -> LDS (reused xsh), kh=0 adds ----
    __syncthreads();                               // all B-reads done; xsh reusable
    float* red = reinterpret_cast<float*>(xsh);    // [(w*64+lane)*20 + 4j+r], 10.2 KB
    float* rb  = red + (w * 64 + lane) * 20;       // stride 20: 16B-aligned
    #pragma unroll
    for (int sl = 0; sl < 5; ++sl) {
        if (kh == 1) {
            #pragma unroll
            for (int j = 0; j < 4; ++j) *(f32x4*)(rb + 4 * j) = acc[sl][j];
        }
        __syncthreads();
        if (kh == 0) {
            #pragma unroll
            for (int j = 0; j < 4; ++j) acc[sl][j] += *(const f32x4*)(rb + 4 * j);
        }
        __syncthreads();
    }

    // ---- epilogue (round-6 verified), kh=0 waves only ----
    // D col=lane&15 -> A-col n, row=grp*4+r -> b; t' = 1024w + 256j + 16n + b.
    // outT2 [n][tb][c][s][16]: lane l owns tb-local = l.
    if (kh == 0) {
        _Float16* os = ostage + 1024 * w;          // wave-local, no barrier needed
        #pragma unroll
        for (int sl = 0; sl < 5; ++sl) {
            #pragma unroll
            for (int j = 0; j < 4; ++j) {
                half4v h;
                #pragma unroll
                for (int r = 0; r < 4; ++r) h[r] = (_Float16)acc[sl][j][r];
                *(half4v*)(os + 256 * j + 16 * mcol + 4 * grp) = h;
            }
            half8 o0 = *(const half8*)(os + 16 * lane);
            half8 o1 = *(const half8*)(os + 16 * lane + 8);
            __half* ob = outT + ((size_t)(((nidx * 128 + 64 * w + lane) * 64 + cidx) * 5 + OS[sl])) * 16;
            *(half8*)(ob)     = o0;
            *(half8*)(ob + 8) = o1;
        }
    }
}

// ---------------- kernel 3: outT2[n][tb][c][s][16] -> out[n][t][c][s] ----------------
// Read side fully contiguous (10 KB per block); LDS transposes [c][s][tt]->[tt][c][s].
__global__ __launch_bounds__(256) void cwt_fix(const __half* __restrict__ outT,
                                               float* __restrict__ out) {
    __shared__ float tile[16 * 320];              // [tt][c*5+s]
    const int b  = blockIdx.x;                    // 0..2047
    const int n  = b >> 7;
    const int tb = b & 127;
    const int tid = threadIdx.x;

    const uint4* src = (const uint4*)(outT + (size_t)(n * 128 + tb) * 5120);
    for (int i = tid; i < 640; i += 256) {
        uint4 v = src[i];                         // 8 halves: (c,s) fixed, tt0..tt0+7
        const __half* h = (const __half*)&v;
        const int h0  = i * 8;
        const int sg  = h0 >> 4;                  // c*5+s
        const int tt0 = h0 & 15;                  // 0 or 8
        #pragma unroll
        for (int k = 0; k < 8; ++k) tile[(tt0 + k) * 320 + sg] = __half2float(h[k]);
    }
    __syncthreads();
    float4* dst = (float4*)(out + (size_t)(n * 2048 + tb * 16) * 320);
    const float4* tl = (const float4*)tile;
    for (int k = tid; k < 1280; k += 256) dst[k] = tl[k];
}

// ---------------- launch ----------------
extern "C" void kernel_launch(void* const* d_in, const int* in_sizes, int n_in,
                              void* d_out, int out_size, void* d_ws, size_t ws_size,
                              hipStream_t stream) {
    const float* x = (const float*)d_in[0];
    float* out = (float*)d_out;
    char* ws = (char*)d_ws;

    __half* W    = (__half*)ws;
    __half* xT   = (__half*)(ws + WS_XT);
    __half* outT = (__half*)(ws + WS_OUTT);

    cwt_prep<<<129, 1024, 0, stream>>>(x, xT, W);
    cwt_conv_mfma<<<NROWS, 256, 0, stream>>>(xT, W, outT);
    cwt_fix<<<2048, 256, 0, stream>>>(outT, out);
}